// Round 15
// baseline (103.175 us; speedup 1.0000x reference)
//
#include <hip/hip_runtime.h>

#define NQ 32768
#define NC 8192
#define CFEAT 128
#define CSPLIT 64
#define TILE (NC / CSPLIT)   // 128 coords per split
#define BLK 256
#define QPT 8                // R15: QPT=8 now that pin removed the VALU bloat
#define QPB (BLK * QPT)      // 2048 queries per block
#define GX (NQ / QPB)        // 16 -> phase-1 grid (16, 64) = 1024 blocks

// ws layout: [0, 8 MB) f32 bestd[NQ][CSPLIT]; then float4 ctab[NC] (128 KB).
//
// NUMERICS IS FROZEN (R3/R4 lesson): per-coord distance chain is exactly
//   t = mul(-2cx, px); t = fma(-2cy, py, t); t = fma(-2cz, pz, t); d = cc + t
// with cc = ((cx*cx + cy*cy) + cz*cz) pinned by asm barrier. Flip-free vs
// np's argmin across 9 passing rounds. pk halves run this exact IEEE-RN
// sequence. Phase 2 reads the SAME stored ctab bits (R1 lesson).
//
// PHASE-1 PIPE MODEL (closed by R14's controlled null result):
//   LDS pipe: waves/CU x 128 ds_read_b128 x 12 cyc
//     QPT=4 -> 20.5 us (binding; why R14's pin was invisible)
//     QPT=8 -> 10.2 us
//   VALU: 11 insts/pair/query unpinned (remat movs) ~= 18.8 us at any QPT
//         5 insts/pair/query pinned             ~= 8.5 us
//   Every earlier experiment moved ONE term while the other sat at ~19-20:
//   R6 (pk alone) neutral, R11 (QPT=8 alone) neutral, R14 (pin alone)
//   neutral. R15 moves both: ~10-12 us phase-1 model, ~16-18 with the
//   observed 1.6x latency factor.
//
// STRUCTURE LESSONS (counter-backed):
//  - R10: no in-loop index tracking (2.5x). Min-only + equality rescan.
//  - R12: uniform global ctab reads stay VMEM (48 us). R13: distributed
//    reads + per-query shfl reduce worse (53 us). LDS broadcast stands.
//  - R5: phase 2 stays wave-per-query, 8192 blocks (max TLP).
//  - R8: no cooperative launch / occupancy queries in kernel_launch.
#define BESTD_OFF 0
#define CTAB_OFF ((size_t)NQ * CSPLIT * 4)

typedef float f32x2 __attribute__((ext_vector_type(2)));

// Phase 1: per-split min DISTANCE only — no index tracking.
// Pair-interleaved LDS ctab (R6-proven): sA[p]=(x0,x1,y0,y1),
// sB[p]=(z0,z1,w0,w1) -> direct pk operands. Inner loop per 2 coords per
// query: v_pk_mul + v_pk_fma + v_pk_fma + v_pk_add + v_min3 = 5 insts,
// with pinned splat pairs NOTHING else.
__global__ __launch_bounds__(BLK, 4) void argmin_split(
    const float* __restrict__ coords, const float* __restrict__ points,
    float* __restrict__ bestd, float4* __restrict__ ctab) {
  __shared__ float4 sA[TILE / 2];
  __shared__ float4 sB[TILE / 2];

  const int s = blockIdx.y;
  const int base = s * TILE;

  if (threadIdx.x < TILE) {
    const int i = base + threadIdx.x;
    const float cx = coords[i * 3 + 0];
    const float cy = coords[i * 3 + 1];
    const float cz = coords[i * 3 + 2];
    float xx = cx * cx, yy = cy * cy, zz = cz * cz;
    // Opaque barrier: forbid contracting these products into the adds.
    asm volatile("" : "+v"(xx), "+v"(yy), "+v"(zz));
    const float cc = (xx + yy) + zz;
    const float4 e = make_float4(-2.0f * cx, -2.0f * cy, -2.0f * cz, cc);
    const int p = threadIdx.x >> 1, hi = threadIdx.x & 1;
    float* a = (float*)&sA[p];
    float* b = (float*)&sB[p];
    a[0 + hi] = e.x;  a[2 + hi] = e.y;
    b[0 + hi] = e.z;  b[2 + hi] = e.w;
    if (blockIdx.x == 0) ctab[i] = e;   // persist exact bits for phase 2
  }

  const int q0 = blockIdx.x * QPB + threadIdx.x;
  f32x2 pxs[QPT], pys[QPT], pzs[QPT];
  float best[QPT];
  #pragma unroll
  for (int k = 0; k < QPT; ++k) {
    const int q = q0 + k * BLK;
    const float x = points[q * 3 + 0];
    const float y = points[q * 3 + 1];
    const float z = points[q * 3 + 2];
    pxs[k] = (f32x2){x, x};
    pys[k] = (f32x2){y, y};
    pzs[k] = (f32x2){z, z};
    // Pin each splat pair into a live VGPR pair: the compiler cannot
    // rematerialize it inside the loop (the R12/R13-diagnosed VALU bloat;
    // R14-proven harmless). Values unchanged.
    asm volatile("" : "+v"(pxs[k]), "+v"(pys[k]), "+v"(pzs[k]));
    best[k] = __builtin_inff();
  }
  __syncthreads();

  #pragma unroll 2
  for (int p = 0; p < TILE / 2; ++p) {
    const float4 a = sA[p];          // uniform addr -> broadcast ds_read_b128
    const float4 b = sB[p];
    const f32x2 X = {a.x, a.y}, Y = {a.z, a.w};
    const f32x2 Z = {b.x, b.y}, W = {b.z, b.w};
    #pragma unroll
    for (int k = 0; k < QPT; ++k) {
      f32x2 t = X * pxs[k];                            // v_pk_mul_f32 (RN)
      t = __builtin_elementwise_fma(Y, pys[k], t);     // v_pk_fma_f32 (RN)
      t = __builtin_elementwise_fma(Z, pzs[k], t);     // v_pk_fma_f32 (RN)
      const f32x2 d = W + t;                           // v_pk_add_f32 (RN)
      best[k] = fminf(fminf(best[k], d.x), d.y);       // v_min3_f32 (exact)
    }
  }

  #pragma unroll
  for (int k = 0; k < QPT; ++k) {
    const int q = q0 + k * BLK;
    bestd[(size_t)q * CSPLIT + s] = best[k];
  }
}

// Phase 2 (R2-proven, verbatim): one wave per query — reduce 64 split-mins
// (shfl min + ballot/ffs -> lowest winning split); equality-rescan that
// split's 128 coords from the SHARED global ctab (same bits + same frozen
// scalar chain as the pk halves -> hit guaranteed; first match = lowest
// coord). Tiebreak == np.argmin's global first-index. Gather feature row,
// 64 lanes x float2.
__global__ __launch_bounds__(256) void rescan_gather(
    const float4* __restrict__ ctab, const float* __restrict__ points,
    const float* __restrict__ bestd, const float* __restrict__ feature,
    float2* __restrict__ out) {
  const int q = blockIdx.x * 4 + (threadIdx.x >> 6);
  const int l = threadIdx.x & 63;

  // lane l holds split l's min — 256 B coalesced read per wave
  const float v = bestd[(size_t)q * CSPLIT + l];
  float m = v;
  #pragma unroll
  for (int off = 32; off; off >>= 1) m = fminf(m, __shfl_xor(m, off, 64));
  const unsigned long long bs = __ballot(v == m);
  const int sstar = __ffsll(bs) - 1;            // lowest split attaining min

  const float qx = points[q * 3 + 0];           // wave-uniform
  const float qy = points[q * 3 + 1];
  const float qz = points[q * 3 + 2];
  const int b2 = sstar * TILE;

  const float4 c0 = ctab[b2 + l];               // coalesced, lanes consecutive
  const float4 c1 = ctab[b2 + 64 + l];
  float t0 = __fmul_rn(c0.x, qx);                      // FROZEN CHAIN (R2)
  t0 = __fmaf_rn(c0.y, qy, t0);
  t0 = __fmaf_rn(c0.z, qz, t0);
  const float d0 = __fadd_rn(c0.w, t0);
  float t1 = __fmul_rn(c1.x, qx);
  t1 = __fmaf_rn(c1.y, qy, t1);
  t1 = __fmaf_rn(c1.z, qz, t1);
  const float d1 = __fadd_rn(c1.w, t1);

  const unsigned long long b0 = __ballot(d0 == m);
  const unsigned long long b1 = __ballot(d1 == m);
  int off_in;
  if (b0 | b1) {
    off_in = b0 ? (__ffsll(b0) - 1) : (64 + __ffsll(b1) - 1);
  } else {
    // Defense in depth (should be unreachable): true argmin over the 128
    // rescanned candidates, first-index tiebreak.
    float dm = fminf(d0, d1);
    int im = (d0 <= d1) ? l : (64 + l);
    #pragma unroll
    for (int off = 32; off; off >>= 1) {
      const float od = __shfl_xor(dm, off, 64);
      const int oi = __shfl_xor(im, off, 64);
      if (od < dm || (od == dm && oi < im)) { dm = od; im = oi; }
    }
    off_in = im;
  }
  const int idx = b2 + off_in;

  const float2* fr = (const float2*)(feature + (size_t)idx * CFEAT);
  out[(size_t)q * (CFEAT / 2) + l] = fr[l];
}

extern "C" void kernel_launch(void* const* d_in, const int* in_sizes, int n_in,
                              void* d_out, int out_size, void* d_ws, size_t ws_size,
                              hipStream_t stream) {
  const float* coords  = (const float*)d_in[0];   // [8192, 3]
  const float* feature = (const float*)d_in[1];   // [8192, 128]
  const float* points  = (const float*)d_in[2];   // [32768, 3]
  float2* out = (float2*)d_out;                   // [32768, 128]

  float* bestd = (float*)((char*)d_ws + BESTD_OFF);
  float4* ctab = (float4*)((char*)d_ws + CTAB_OFF);

  dim3 grid1(GX, CSPLIT);                         // (16, 64) = 1024 blocks
  argmin_split<<<grid1, BLK, 0, stream>>>(coords, points, bestd, ctab);

  rescan_gather<<<NQ / 4, 256, 0, stream>>>(ctab, points, bestd, feature,
                                            out);
}